// Round 14
// baseline (131.505 us; speedup 1.0000x reference)
//
#include <hip/hip_runtime.h>
#include <hip/hip_bf16.h>
#include <hip/hip_fp16.h>
#include <math.h>

#define NNODES 50000
#define NPAD   50048   // padded row count (multiple of 64)
#define KNEI 16

typedef __attribute__((ext_vector_type(8))) short bf8;
typedef __attribute__((ext_vector_type(4))) float f32x4;

static __device__ __forceinline__ unsigned int f2bf(float f) {
    __hip_bfloat16 h = __float2bfloat16(f);
    return (unsigned int)*reinterpret_cast<unsigned short*>(&h);
}
static __device__ __forceinline__ unsigned short f2h(float f) {
    __half h = __float2half(f);
    return *reinterpret_cast<unsigned short*>(&h);
}
static __device__ __forceinline__ float2 h2f2(unsigned int u) {
    __half2 h = *reinterpret_cast<__half2*>(&u);
    return __half22float2(h);
}

// ---------------------------------------------------------------------------
// prep_bt: BT[c][k] = bf16(Wc[k][c]), c in 0..255, k in 0..127 (64 KB).
// Wc[k][c] = c<128 ? W[k][c] - W[k+128][c] : W[k+128][c-128]
// ---------------------------------------------------------------------------
__global__ __launch_bounds__(128) void prep_bt(const float* __restrict__ W,
                                               unsigned short* __restrict__ BT) {
    int c = blockIdx.x;      // 0..255
    int k = threadIdx.x;     // 0..127
    float v;
    if (c < 128) v = W[k * 128 + c] - W[(k + 128) * 128 + c];
    else         v = W[(k + 128) * 128 + (c - 128)];
    BT[c * 128 + k] = (unsigned short)f2bf(v);
}

// ---------------------------------------------------------------------------
// prep_xb: xb = bf16(x), padded with zero rows to NPAD. 8 elems/thread.
// 50048*128/8/256 = 3128 blocks exactly.
// ---------------------------------------------------------------------------
__global__ __launch_bounds__(256) void prep_xb(const float* __restrict__ x,
                                               unsigned short* __restrict__ xb) {
    size_t e = ((size_t)blockIdx.x * 256 + threadIdx.x) * 8;
    int row = (int)(e >> 7);
    uint4 o = make_uint4(0, 0, 0, 0);
    if (row < NNODES) {
        float4 v0 = *(const float4*)&x[e];
        float4 v1 = *(const float4*)&x[e + 4];
        o.x = f2bf(v0.x) | (f2bf(v0.y) << 16);
        o.y = f2bf(v0.z) | (f2bf(v0.w) << 16);
        o.z = f2bf(v1.x) | (f2bf(v1.y) << 16);
        o.w = f2bf(v1.z) | (f2bf(v1.w) << 16);
    }
    *(uint4*)&xb[e] = o;
}

// ---------------------------------------------------------------------------
// gemm_bf16: NO LDS, NO barriers. 782 blocks x 256 thr (4 waves).
// Tile 64 rows x 256 cols; wave w owns cols [64w,64w+64) (4 n-frags x 4 m-frags).
// A-frags: direct 16B loads from pre-converted xb (zero-padded -> no guards).
// B-frags: direct 16B loads from BT (64 KB, L1/L2-hot).
// k-loop = 32 loads + 64 MFMA per thread, fully pipelineable, max MLP.
// Epilogue: direct scalar fp16 stores (D: col=lane&15, row=(lane>>4)*4+reg).
// ---------------------------------------------------------------------------
__global__ __launch_bounds__(256) void gemm_bf16(const unsigned short* __restrict__ xb,
                                                 const unsigned short* __restrict__ BT,
                                                 const float* __restrict__ bias,
                                                 unsigned short* __restrict__ Ph,
                                                 unsigned short* __restrict__ Qh) {
    const int t  = threadIdx.x;
    const int w  = t >> 6;          // wave 0..3
    const int l  = t & 63;          // lane
    const int lr = l & 15;          // row/col within frag
    const int lk = (l >> 4) * 8;    // k-offset within frag
    const int row0 = blockIdx.x * 64;
    const int colG0 = w * 64 + lr;  // global col of n-frag 0

    const unsigned short* bt0 = BT + colG0 * 128 + lk;
    const unsigned short* a0  = xb + (size_t)(row0 + lr) * 128 + lk;

    float bb[4];
    #pragma unroll
    for (int n = 0; n < 4; ++n) {
        int col = colG0 + n * 16;
        bb[n] = (col < 128) ? bias[col] : 0.f;
    }

    f32x4 acc[4][4];
    #pragma unroll
    for (int m = 0; m < 4; ++m)
        #pragma unroll
        for (int n = 0; n < 4; ++n) acc[m][n] = (f32x4){0.f, 0.f, 0.f, 0.f};

    #pragma unroll
    for (int s = 0; s < 4; ++s) {
        const int kp = s * 32;
        bf8 a[4], b[4];
        #pragma unroll
        for (int m = 0; m < 4; ++m)
            a[m] = *(const bf8*)(a0 + (size_t)m * 16 * 128 + kp);
        #pragma unroll
        for (int n = 0; n < 4; ++n)
            b[n] = *(const bf8*)(bt0 + n * 16 * 128 + kp);
        #pragma unroll
        for (int m = 0; m < 4; ++m)
            #pragma unroll
            for (int n = 0; n < 4; ++n)
                acc[m][n] = __builtin_amdgcn_mfma_f32_16x16x32_bf16(a[m], b[n], acc[m][n], 0, 0, 0);
    }

    // epilogue: direct scalar fp16 stores
    #pragma unroll
    for (int m = 0; m < 4; ++m) {
        #pragma unroll
        for (int n = 0; n < 4; ++n) {
            const int col = colG0 + n * 16;
            unsigned short* base = (col < 128) ? (Ph + col) : (Qh + (col - 128));
            #pragma unroll
            for (int i = 0; i < 4; ++i) {
                int row = row0 + m * 16 + (l >> 4) * 4 + i;
                if (row < NNODES)
                    base[(size_t)row * 128] = f2h(acc[m][n][i] + bb[n]);
            }
        }
    }
}

// ---------------------------------------------------------------------------
// gather_max: out[n,o] = elu(P[n,o] + max_valid_k Q[edge[n,k],o])  (ELU monotone)
// fp16 P/Q. 16 nodes/block, 16 thr/node, 8 halves (uint4) per thread.
// All 16 gathers issued first (MLP=16); masked k substitutes always-valid e[0].
// ---------------------------------------------------------------------------
__global__ __launch_bounds__(256) void gather_max(const unsigned short* __restrict__ Ph,
                                                  const unsigned short* __restrict__ Qh,
                                                  const int* __restrict__ edge,
                                                  float* __restrict__ out) {
    const int t  = threadIdx.x;
    const int n  = blockIdx.x * 16 + (t >> 4);   // 50000 = 16 * 3125
    const int o8 = (t & 15) * 8;

    const int4* er = (const int4*)(edge + n * KNEI);
    int4 e0 = er[0], e1 = er[1], e2 = er[2], e3 = er[3];
    int ia[16] = {e0.x, e0.y, e0.z, e0.w, e1.x, e1.y, e1.z, e1.w,
                  e2.x, e2.y, e2.z, e2.w, e3.x, e3.y, e3.z, e3.w};
    const int s0 = ia[0];                        // k=0 never masked
    const unsigned short* qb = Qh + o8;

    uint4 q[16];
    #pragma unroll
    for (int k = 0; k < 16; ++k) {
        int ix = ia[k] < 0 ? s0 : ia[k];
        q[k] = *(const uint4*)(qb + (size_t)ix * 128);
    }
    uint4 pv = *(const uint4*)(Ph + (size_t)n * 128 + o8);

    float2 m0 = h2f2(q[0].x), m1 = h2f2(q[0].y), m2 = h2f2(q[0].z), m3 = h2f2(q[0].w);
    #pragma unroll
    for (int k = 1; k < 16; ++k) {
        float2 a0 = h2f2(q[k].x), a1 = h2f2(q[k].y), a2 = h2f2(q[k].z), a3 = h2f2(q[k].w);
        m0.x = fmaxf(m0.x, a0.x); m0.y = fmaxf(m0.y, a0.y);
        m1.x = fmaxf(m1.x, a1.x); m1.y = fmaxf(m1.y, a1.y);
        m2.x = fmaxf(m2.x, a2.x); m2.y = fmaxf(m2.y, a2.y);
        m3.x = fmaxf(m3.x, a3.x); m3.y = fmaxf(m3.y, a3.y);
    }
    float2 p0 = h2f2(pv.x), p1 = h2f2(pv.y), p2 = h2f2(pv.z), p3 = h2f2(pv.w);

    float z[8] = {p0.x + m0.x, p0.y + m0.y, p1.x + m1.x, p1.y + m1.y,
                  p2.x + m2.x, p2.y + m2.y, p3.x + m3.x, p3.y + m3.y};
    float r[8];
    #pragma unroll
    for (int i = 0; i < 8; ++i) r[i] = z[i] > 0.f ? z[i] : expm1f(z[i]);

    float* ob = out + (size_t)n * 128 + o8;
    *(float4*)ob       = make_float4(r[0], r[1], r[2], r[3]);
    *(float4*)(ob + 4) = make_float4(r[4], r[5], r[6], r[7]);
}

extern "C" void kernel_launch(void* const* d_in, const int* in_sizes, int n_in,
                              void* d_out, int out_size, void* d_ws, size_t ws_size,
                              hipStream_t stream) {
    const float* x    = (const float*)d_in[0];
    const int*   edge = (const int*)d_in[1];
    const float* W    = (const float*)d_in[2];
    const float* bias = (const float*)d_in[3];
    float* out = (float*)d_out;

    unsigned short* Qh = (unsigned short*)d_ws;              // 12.8 MB
    unsigned short* Ph = Qh + 6400000;                       // 12.8 MB
    unsigned short* BT = Qh + 12800000;                      // 64 KB
    unsigned short* xb = Qh + 12832768;                      // 12.8 MB (NPAD rows)

    prep_bt<<<256, 128, 0, stream>>>(W, BT);
    prep_xb<<<(NPAD * 128) / (8 * 256), 256, 0, stream>>>(x, xb);
    gemm_bf16<<<NPAD / 64, 256, 0, stream>>>(xb, BT, bias, Ph, Qh);
    gather_max<<<NNODES / 16, 256, 0, stream>>>(Ph, Qh, edge, out);
}